// Round 2
// baseline (506.314 us; speedup 1.0000x reference)
//
#include <hip/hip_runtime.h>
#include <stdint.h>

#define NTOT 8192
#define BHALF 4096
#define DZ 512
#define DC 128
#define CS 8
#define COLS_PER_BLK (NTOT / CS)   // 1024
#define TEMPV 0.5f

typedef __attribute__((ext_vector_type(8))) short short8;     // 8 bf16 (4 VGPRs)
typedef __attribute__((ext_vector_type(16))) float f32x16;
typedef __attribute__((ext_vector_type(4))) float floatx4;
typedef __attribute__((ext_vector_type(4))) unsigned short u16x4;
typedef unsigned short u16;

__device__ __forceinline__ u16 f2bf(float x) {
  uint32_t u = __builtin_bit_cast(uint32_t, x);
  u += 0x7fffu + ((u >> 16) & 1u);   // RNE
  return (u16)(u >> 16);
}

// ---------------- convert: fp32 -> bf16 (z = [z_i;z_j], c = [c_i;c_j]) ----------------
__global__ void convert_kernel(const float* __restrict__ z_i, const float* __restrict__ z_j,
                               const float* __restrict__ c_i, const float* __restrict__ c_j,
                               u16* __restrict__ zb, u16* __restrict__ cb) {
  const int NZ4 = NTOT * DZ / 4;
  const int NC4 = NTOT * DC / 4;
  int stride = gridDim.x * blockDim.x;
  for (int i = blockIdx.x * blockDim.x + threadIdx.x; i < NZ4 + NC4; i += stride) {
    if (i < NZ4) {
      int flat = i * 4;
      int r = flat >> 9, d = flat & (DZ - 1);
      const float* src = (r < BHALF) ? (z_i + (size_t)r * DZ + d)
                                     : (z_j + (size_t)(r - BHALF) * DZ + d);
      floatx4 v = *(const floatx4*)src;
      u16x4 o;
      o[0] = f2bf(v[0]); o[1] = f2bf(v[1]); o[2] = f2bf(v[2]); o[3] = f2bf(v[3]);
      *(u16x4*)(zb + flat) = o;
    } else {
      int flat = (i - NZ4) * 4;
      int r = flat >> 7, d = flat & (DC - 1);
      const float* src = (r < BHALF) ? (c_i + (size_t)r * DC + d)
                                     : (c_j + (size_t)(r - BHALF) * DC + d);
      floatx4 v = *(const floatx4*)src;
      u16x4 o;
      o[0] = f2bf(v[0]); o[1] = f2bf(v[1]); o[2] = f2bf(v[2]); o[3] = f2bf(v[3]);
      *(u16x4*)(cb + flat) = o;
    }
  }
}

// ---------------- fused flash-style lse kernel, 32x32x16 MFMA ----------------
// block: 4 waves x 32 rows = 128 rows; columns [cs*1024, cs*1024+1024), 32 cols/iter.
// cs = blockIdx & 7 so the round-robin XCD assignment gives each XCD one column
// stripe (1.25 MB) -> L2-resident.
// LDS tile: 16B chunks, chunk(row n, chunk c) stored at n*CPR + (c ^ (n&7)):
// every 8 consecutive lanes of a B-frag ds_read_b128 hit 8 distinct bank-quads.
__launch_bounds__(256, 2)
__global__ void fused_kernel(const u16* __restrict__ zb, const u16* __restrict__ cb,
                             float* __restrict__ lse_part, float* __restrict__ posArr) {
  __shared__ __align__(16) u16 zT[32 * DZ];  // 32 KB
  __shared__ __align__(16) u16 cT[32 * DC];  // 8 KB

  const int tid  = threadIdx.x;
  const int w    = tid >> 6;
  const int lane = tid & 63;
  const int half = lane >> 5;   // 0/1
  const int n32  = lane & 31;

  const int cs = blockIdx.x & 7;
  const int rb = blockIdx.x >> 3;
  const int row_w    = rb * 128 + w * 32;          // this wave's 32 rows
  const int col_base = cs * COLS_PER_BLK;

  // A fragments in registers: lane holds A[m = n32][k = kk*16 + half*8 + j]
  short8 a_z[32];
  short8 a_c[8];
  {
    const u16* pz = zb + (size_t)(row_w + n32) * DZ + half * 8;
#pragma unroll
    for (int kk = 0; kk < 32; ++kk) a_z[kk] = *(const short8*)(pz + kk * 16);
    const u16* pc = cb + (size_t)(row_w + n32) * DC + half * 8;
#pragma unroll
    for (int kk = 0; kk < 8; ++kk) a_c[kk] = *(const short8*)(pc + kk * 16);
  }

  float m_[16], l_[16];
#pragma unroll
  for (int r = 0; r < 16; ++r) { m_[r] = -3.0e38f; l_[r] = 0.0f; }

  for (int it = 0; it < COLS_PER_BLK / 32; ++it) {   // 32 iterations
    const int col0 = col_base + it * 32;
    __syncthreads();   // previous iteration's LDS reads done

    // stage z tile: 32 rows x 64 chunks; 8 calls/wave, one full row per call
#pragma unroll
    for (int c4 = 0; c4 < 8; ++c4) {
      const int rn = c4 * 4 + w;
      const int cc = lane ^ (rn & 7);
      const u16* src = zb + (size_t)(col0 + rn) * DZ + cc * 8;
      u16* dst = &zT[rn * 64 * 8];   // wave-uniform base, lane*16 implicit
      __builtin_amdgcn_global_load_lds((const __attribute__((address_space(1))) void*)src,
                                       (__attribute__((address_space(3))) void*)dst, 16, 0, 0);
    }
    // stage c tile: 32 rows x 16 chunks; 2 calls/wave, 4 rows per call
#pragma unroll
    for (int h = 0; h < 2; ++h) {
      const int grp = h * 4 + w;                  // 64-chunk group
      const int rn  = grp * 4 + (lane >> 4);
      const int cc  = (lane & 15) ^ (rn & 7);
      const u16* src = cb + (size_t)(col0 + rn) * DC + cc * 8;
      u16* dst = &cT[grp * 64 * 8];
      __builtin_amdgcn_global_load_lds((const __attribute__((address_space(1))) void*)src,
                                       (__attribute__((address_space(3))) void*)dst, 16, 0, 0);
    }
    __syncthreads();   // vmcnt(0) drained before barrier -> staged data visible

    // B frag for lane: B[k = kk*16 + half*8 + j][n = n32] -> LDS row n32, chunk kk*2+half
    f32x16 accc;
#pragma unroll
    for (int r = 0; r < 16; ++r) accc[r] = 0.0f;
#pragma unroll
    for (int kk = 0; kk < 8; ++kk) {
      const int cc = kk * 2 + half;
      const short8 b = *(const short8*)&cT[(n32 * 16 + (cc ^ (n32 & 7))) * 8];
      accc = __builtin_amdgcn_mfma_f32_32x32x16_bf16(a_c[kk], b, accc, 0, 0, 0);
    }
    f32x16 accz;
#pragma unroll
    for (int r = 0; r < 16; ++r) accz[r] = 0.0f;
#pragma unroll
    for (int kk = 0; kk < 32; ++kk) {
      const int cc = kk * 2 + half;
      const short8 b = *(const short8*)&zT[(n32 * 64 + (cc ^ (n32 & 7))) * 8];
      accz = __builtin_amdgcn_mfma_f32_32x32x16_bf16(a_z[kk], b, accz, 0, 0, 0);
    }

    // epilogue: C/D col = lane&31, row = (reg&3) + 8*(reg>>2) + 4*(lane>>5)
    const int gc = col0 + n32;
#pragma unroll
    for (int r = 0; r < 16; ++r) {
      const int gr = row_w + (r & 3) + 8 * (r >> 2) + 4 * half;
      float tv = fmaxf(accc[r], TEMPV);
      const bool isPair = (gc == (gr ^ BHALF));   // (i+B)%N == i^B for pow2
      const bool isDiag = (gc == gr);
      if (isPair) tv = TEMPV;
      float s = accz[r] * __builtin_amdgcn_rcpf(tv);
      if (isPair) posArr[gr] = s;                 // exactly one writer per row
      float sm = isDiag ? -3.0e38f : s;
      float mn = fmaxf(m_[r], sm);
      float e  = isDiag ? 0.0f : __expf(s - mn);
      l_[r] = l_[r] * __expf(m_[r] - mn) + e;
      m_[r] = mn;
    }
  }

  // merge 32 column-lanes per half (rows of the two halves are disjoint; xor<=16
  // stays within a half), write partial lse
#pragma unroll
  for (int r = 0; r < 16; ++r) {
    float mm = m_[r], ll = l_[r];
#pragma unroll
    for (int off = 1; off < 32; off <<= 1) {
      float m2 = __shfl_xor(mm, off);
      float l2 = __shfl_xor(ll, off);
      float mx = fmaxf(mm, m2);
      ll = ll * __expf(mm - mx) + l2 * __expf(m2 - mx);
      mm = mx;
    }
    if (n32 == 0) {
      const int gr = row_w + (r & 3) + 8 * (r >> 2) + 4 * half;
      lse_part[(size_t)cs * NTOT + gr] = mm + __logf(ll);
    }
  }
}

// ---------------- finalize: merge 8 column-split partial lse's, reduce ----------------
__global__ void finalize_kernel(const float* __restrict__ lse_part,
                                const float* __restrict__ posArr,
                                float* __restrict__ out) {
  __shared__ float red[1024];
  float acc = 0.0f;
  for (int row = threadIdx.x; row < NTOT; row += 1024) {
    float p[CS];
    float M = -3.0e38f;
#pragma unroll
    for (int s = 0; s < CS; ++s) {
      p[s] = lse_part[(size_t)s * NTOT + row];
      M = fmaxf(M, p[s]);
    }
    float sum = 0.0f;
#pragma unroll
    for (int s = 0; s < CS; ++s) sum += __expf(p[s] - M);
    acc += (M + __logf(sum)) - posArr[row];
  }
  red[threadIdx.x] = acc;
  __syncthreads();
  for (int s = 512; s > 0; s >>= 1) {
    if ((int)threadIdx.x < s) red[threadIdx.x] += red[threadIdx.x + s];
    __syncthreads();
  }
  if (threadIdx.x == 0) out[0] = red[0] * (1.0f / NTOT);
}

extern "C" void kernel_launch(void* const* d_in, const int* in_sizes, int n_in,
                              void* d_out, int out_size, void* d_ws, size_t ws_size,
                              hipStream_t stream) {
  const float* z_i = (const float*)d_in[0];
  const float* z_j = (const float*)d_in[1];
  const float* c_i = (const float*)d_in[2];
  const float* c_j = (const float*)d_in[3];

  u16* zb = (u16*)d_ws;                              // 8192*512 bf16 = 8 MB
  u16* cb = zb + (size_t)NTOT * DZ;                  // 8192*128 bf16 = 2 MB
  float* lse_part = (float*)(cb + (size_t)NTOT * DC); // 8*8192 f32
  float* posArr   = lse_part + (size_t)CS * NTOT;     // 8192 f32

  convert_kernel<<<2560, 256, 0, stream>>>(z_i, z_j, c_i, c_j, zb, cb);
  fused_kernel<<<512, 256, 0, stream>>>(zb, cb, lse_part, posArr);
  finalize_kernel<<<1, 1024, 0, stream>>>(lse_part, posArr, (float*)d_out);
}

// Round 3
// 214.457 us; speedup vs baseline: 2.3609x; 2.3609x over previous
//
#include <hip/hip_runtime.h>
#include <stdint.h>

#define NTOT 8192
#define BHALF 4096
#define DZ 512
#define DC 128
#define CS 8
#define COLS_PER_BLK (NTOT / CS)   // 1024
#define TEMPV 0.5f

typedef __attribute__((ext_vector_type(8))) short short8;     // 8 bf16 (4 VGPRs)
typedef __attribute__((ext_vector_type(4))) float f32x4;
typedef __attribute__((ext_vector_type(4))) float floatx4;
typedef __attribute__((ext_vector_type(4))) unsigned short u16x4;
typedef unsigned short u16;

__device__ __forceinline__ u16 f2bf(float x) {
  uint32_t u = __builtin_bit_cast(uint32_t, x);
  u += 0x7fffu + ((u >> 16) & 1u);   // RNE
  return (u16)(u >> 16);
}

#define MFMA16(a, b, c) __builtin_amdgcn_mfma_f32_16x16x32_bf16((a), (b), (c), 0, 0, 0)

// ---------------- convert: fp32 -> bf16 (z = [z_i;z_j], c = [c_i;c_j]) ----------------
__global__ void convert_kernel(const float* __restrict__ z_i, const float* __restrict__ z_j,
                               const float* __restrict__ c_i, const float* __restrict__ c_j,
                               u16* __restrict__ zb, u16* __restrict__ cb) {
  const int NZ4 = NTOT * DZ / 4;
  const int NC4 = NTOT * DC / 4;
  int stride = gridDim.x * blockDim.x;
  for (int i = blockIdx.x * blockDim.x + threadIdx.x; i < NZ4 + NC4; i += stride) {
    if (i < NZ4) {
      int flat = i * 4;
      int r = flat >> 9, d = flat & (DZ - 1);
      const float* src = (r < BHALF) ? (z_i + (size_t)r * DZ + d)
                                     : (z_j + (size_t)(r - BHALF) * DZ + d);
      floatx4 v = *(const floatx4*)src;
      u16x4 o;
      o[0] = f2bf(v[0]); o[1] = f2bf(v[1]); o[2] = f2bf(v[2]); o[3] = f2bf(v[3]);
      *(u16x4*)(zb + flat) = o;
    } else {
      int flat = (i - NZ4) * 4;
      int r = flat >> 7, d = flat & (DC - 1);
      const float* src = (r < BHALF) ? (c_i + (size_t)r * DC + d)
                                     : (c_j + (size_t)(r - BHALF) * DC + d);
      floatx4 v = *(const floatx4*)src;
      u16x4 o;
      o[0] = f2bf(v[0]); o[1] = f2bf(v[1]); o[2] = f2bf(v[2]); o[3] = f2bf(v[3]);
      *(u16x4*)(cb + flat) = o;
    }
  }
}

// ---------------- fused flash-style lse kernel ----------------
// 16x16x32 MFMA, 2 A-sets per wave (32 rows), block = 4 waves = 128 rows.
// Columns [cs*1024, cs*1024+1024), 16 cols/iter, 64 iters. cs = blockIdx&7 -> one
// column stripe per XCD (B-stripe 1.25 MB L2-resident).
// LDS B-tile layout (k-major, conflict-free): 16B chunk for (col n, k-chunk kc)
// stored at chunk index (kc>>2)*64 + (kc&3)*16 + n. MFMA frag kk reads chunks
// kk*64 + lane -> ds_read_b128 at base+16*lane, zero bank conflicts (m134 pattern).
__launch_bounds__(256, 2)
__global__ void fused_kernel(const u16* __restrict__ zb, const u16* __restrict__ cb,
                             float* __restrict__ lse_part, float* __restrict__ posArr) {
  __shared__ __align__(16) u16 zT[16 * DZ];  // 16 KB: 1024 chunks
  __shared__ __align__(16) u16 cT[16 * DC];  // 4 KB: 256 chunks

  const int tid  = threadIdx.x;
  const int w    = tid >> 6;
  const int lane = tid & 63;
  const int lq   = lane >> 4;   // quad id 0..3
  const int ln   = lane & 15;   // col / A-row index

  const int cs = blockIdx.x & 7;
  const int rb = blockIdx.x >> 3;
  const int row_w    = rb * 128 + w * 32;          // wave's 32 rows (2 sets of 16)
  const int col_base = cs * COLS_PER_BLK;

  // A fragments in registers: lane holds A[m=ln][k = kk*32 + lq*8 + j]
  short8 a_z0[16], a_z1[16];
  short8 a_c0[4],  a_c1[4];
  {
    const u16* p0 = zb + (size_t)(row_w + ln) * DZ + lq * 8;
    const u16* p1 = zb + (size_t)(row_w + 16 + ln) * DZ + lq * 8;
#pragma unroll
    for (int kk = 0; kk < 16; ++kk) {
      a_z0[kk] = *(const short8*)(p0 + kk * 32);
      a_z1[kk] = *(const short8*)(p1 + kk * 32);
    }
    const u16* q0 = cb + (size_t)(row_w + ln) * DC + lq * 8;
    const u16* q1 = cb + (size_t)(row_w + 16 + ln) * DC + lq * 8;
#pragma unroll
    for (int kk = 0; kk < 4; ++kk) {
      a_c0[kk] = *(const short8*)(q0 + kk * 32);
      a_c1[kk] = *(const short8*)(q1 + kk * 32);
    }
  }

  float m0_[4], l0_[4], m1_[4], l1_[4];
#pragma unroll
  for (int r = 0; r < 4; ++r) {
    m0_[r] = -3.0e38f; l0_[r] = 0.0f;
    m1_[r] = -3.0e38f; l1_[r] = 0.0f;
  }

  for (int it = 0; it < COLS_PER_BLK / 16; ++it) {   // 64 iterations
    const int col0 = col_base + it * 16;
    __syncthreads();   // previous iteration's LDS reads done

    // stage z B-tile: 1024 chunks; wave w issues calls j = w, 4+w, 8+w, 12+w.
    // call j, lane l: LDS chunk j*64+l <- zb[col0 + (l&15)][(j*4 + (l>>4))*8 ..]
#pragma unroll
    for (int c4 = 0; c4 < 4; ++c4) {
      const int j = c4 * 4 + w;
      const u16* src = zb + (size_t)(col0 + ln) * DZ + (j * 4 + lq) * 8;
      u16* dst = &zT[j * 64 * 8];   // wave-uniform base; lane*16 implicit
      __builtin_amdgcn_global_load_lds((const __attribute__((address_space(1))) void*)src,
                                       (__attribute__((address_space(3))) void*)dst, 16, 0, 0);
    }
    // stage c B-tile: 256 chunks; wave w issues call w
    {
      const u16* src = cb + (size_t)(col0 + ln) * DC + (w * 4 + lq) * 8;
      u16* dst = &cT[w * 64 * 8];
      __builtin_amdgcn_global_load_lds((const __attribute__((address_space(1))) void*)src,
                                       (__attribute__((address_space(3))) void*)dst, 16, 0, 0);
    }
    __syncthreads();   // vmcnt(0) drained before barrier -> staged data visible

    f32x4 accc0 = {0.f,0.f,0.f,0.f}, accc1 = {0.f,0.f,0.f,0.f};
#pragma unroll
    for (int kk = 0; kk < 4; ++kk) {
      const short8 b = *(const short8*)&cT[(kk * 64 + lane) * 8];
      accc0 = MFMA16(a_c0[kk], b, accc0);
      accc1 = MFMA16(a_c1[kk], b, accc1);
    }
    f32x4 accz0 = {0.f,0.f,0.f,0.f}, accz1 = {0.f,0.f,0.f,0.f};
#pragma unroll
    for (int kk = 0; kk < 16; ++kk) {
      const short8 b = *(const short8*)&zT[(kk * 64 + lane) * 8];
      accz0 = MFMA16(a_z0[kk], b, accz0);
      accz1 = MFMA16(a_z1[kk], b, accz1);
    }

    // epilogue: C/D col = ln, row = lq*4 + r (set0: row_w+, set1: row_w+16+)
    const int gc = col0 + ln;
#pragma unroll
    for (int s = 0; s < 2; ++s) {
      const f32x4 az = s ? accz1 : accz0;
      const f32x4 ac = s ? accc1 : accc0;
      float* m_ = s ? m1_ : m0_;
      float* l_ = s ? l1_ : l0_;
      const int base_r = row_w + s * 16 + lq * 4;
#pragma unroll
      for (int r = 0; r < 4; ++r) {
        const int gr = base_r + r;
        float tv = fmaxf(ac[r], TEMPV);
        const bool isPair = (gc == (gr ^ BHALF));   // (i+B)%N == i^B for pow2
        const bool isDiag = (gc == gr);
        if (isPair) tv = TEMPV;
        float sv = az[r] * __builtin_amdgcn_rcpf(tv);
        if (isPair) posArr[gr] = sv;                // one writer per row
        // single-exp online update; diag contributes nothing
        float d = sv - m_[r];
        bool grow = (d > 0.0f) && !isDiag;
        float e = __expf(fminf(d, -d));             // exp(-|d|)
        if (isDiag) e = 0.0f;
        l_[r] = grow ? (l_[r] * e + 1.0f) : (l_[r] + e);
        m_[r] = grow ? sv : m_[r];
      }
    }
  }

  // merge the 16 column-lanes (xor offs 1..8 stay within the lq quad-group)
#pragma unroll
  for (int s = 0; s < 2; ++s) {
    float* m_ = s ? m1_ : m0_;
    float* l_ = s ? l1_ : l0_;
    const int base_r = row_w + s * 16 + lq * 4;
#pragma unroll
    for (int r = 0; r < 4; ++r) {
      float mm = m_[r], ll = l_[r];
#pragma unroll
      for (int off = 1; off < 16; off <<= 1) {
        float m2 = __shfl_xor(mm, off);
        float l2 = __shfl_xor(ll, off);
        float mx = fmaxf(mm, m2);
        ll = ll * __expf(mm - mx) + l2 * __expf(m2 - mx);
        mm = mx;
      }
      if (ln == 0) lse_part[(size_t)cs * NTOT + base_r + r] = mm + __logf(ll);
    }
  }
}

// ---------------- finalize stage 1: 32 blocks x 256 rows -> partial sums ----------------
__global__ void finalize1_kernel(const float* __restrict__ lse_part,
                                 const float* __restrict__ posArr,
                                 float* __restrict__ partial) {
  const int row = blockIdx.x * 256 + threadIdx.x;
  float p[CS];
  float M = -3.0e38f;
#pragma unroll
  for (int s = 0; s < CS; ++s) {
    p[s] = lse_part[(size_t)s * NTOT + row];
    M = fmaxf(M, p[s]);
  }
  float sum = 0.0f;
#pragma unroll
  for (int s = 0; s < CS; ++s) sum += __expf(p[s] - M);
  float v = (M + __logf(sum)) - posArr[row];

  // reduce 256 values: wave shuffle + LDS across 4 waves
#pragma unroll
  for (int off = 32; off > 0; off >>= 1) v += __shfl_xor(v, off);
  __shared__ float red[4];
  const int w = threadIdx.x >> 6;
  if ((threadIdx.x & 63) == 0) red[w] = v;
  __syncthreads();
  if (threadIdx.x == 0) partial[blockIdx.x] = red[0] + red[1] + red[2] + red[3];
}

// ---------------- finalize stage 2: merge 32 partials ----------------
__global__ void finalize2_kernel(const float* __restrict__ partial, float* __restrict__ out) {
  float v = (threadIdx.x < 32) ? partial[threadIdx.x] : 0.0f;
#pragma unroll
  for (int off = 32; off > 0; off >>= 1) v += __shfl_xor(v, off);
  if (threadIdx.x == 0) out[0] = v * (1.0f / NTOT);
}

extern "C" void kernel_launch(void* const* d_in, const int* in_sizes, int n_in,
                              void* d_out, int out_size, void* d_ws, size_t ws_size,
                              hipStream_t stream) {
  const float* z_i = (const float*)d_in[0];
  const float* z_j = (const float*)d_in[1];
  const float* c_i = (const float*)d_in[2];
  const float* c_j = (const float*)d_in[3];

  u16* zb = (u16*)d_ws;                               // 8192*512 bf16 = 8 MB
  u16* cb = zb + (size_t)NTOT * DZ;                   // 8192*128 bf16 = 2 MB
  float* lse_part = (float*)(cb + (size_t)NTOT * DC); // 8*8192 f32 = 256 KB
  float* posArr   = lse_part + (size_t)CS * NTOT;     // 8192 f32 = 32 KB
  float* partial  = posArr + NTOT;                    // 32 f32

  convert_kernel<<<2560, 256, 0, stream>>>(z_i, z_j, c_i, c_j, zb, cb);
  fused_kernel<<<512, 256, 0, stream>>>(zb, cb, lse_part, posArr);
  finalize1_kernel<<<32, 256, 0, stream>>>(lse_part, posArr, partial);
  finalize2_kernel<<<1, 64, 0, stream>>>(partial, (float*)d_out);
}